// Round 6
// baseline (1143.170 us; speedup 1.0000x reference)
//
#include <hip/hip_runtime.h>
#include <stdint.h>

typedef __attribute__((ext_vector_type(8))) short short8;
typedef __attribute__((ext_vector_type(4))) float f32x4;

__device__ __forceinline__ float bf2f(unsigned short u) {
  union { unsigned int i; float f; } v; v.i = ((unsigned int)u) << 16; return v.f;
}
__device__ __forceinline__ unsigned short f2bf(float f) {
  union { float f; unsigned int i; } v; v.f = f;
  unsigned int u = v.i;
  return (unsigned short)((u + 0x7fffu + ((u >> 16) & 1u)) >> 16);
}

#define B_SZ 2
#define T_SEQ 2048
#define NH 16
#define DH 128
#define ROPE_R 32
#define SCALE_Q 0.08838834764831845f

// Load 8 consecutive elements as bf16 fragment; F=true -> source is fp32.
template <bool F>
__device__ __forceinline__ short8 ld8(const void* base, size_t idx) {
  if constexpr (F) {
    const float* p = (const float*)base + idx;
    f32x4 a = *(const f32x4*)p;
    f32x4 b = *(const f32x4*)(p + 4);
    short8 r;
    r[0] = (short)f2bf(a[0]); r[1] = (short)f2bf(a[1]);
    r[2] = (short)f2bf(a[2]); r[3] = (short)f2bf(a[3]);
    r[4] = (short)f2bf(b[0]); r[5] = (short)f2bf(b[1]);
    r[6] = (short)f2bf(b[2]); r[7] = (short)f2bf(b[3]);
    return r;
  } else {
    return *(const short8*)((const unsigned short*)base + idx);
  }
}

// ---------------------------------------------------------------------------
// C[M][N] = A[M][K] @ B[N][K]^T ; bf16 internal, fp32 accum.
// AF/BF: operand source is fp32 (converted during LDS staging).
// C32: store C as fp32 (final output) else bf16.
// 128x128 tile, BK=32, 4 waves (2x2), each wave 4x4 of 16x16x32 MFMA.
// ---------------------------------------------------------------------------
template <bool AF, bool BF, bool C32>
__global__ __launch_bounds__(256) void gemm_bt(
    const void* __restrict__ Ap, const void* __restrict__ Bp,
    void* __restrict__ Cp, int M, int N, int K) {
  __shared__ unsigned short Al[128][40];
  __shared__ unsigned short Bl[128][40];
  const int tid = threadIdx.x;
  const int lane = tid & 63, w = tid >> 6;
  const int wm = w >> 1, wn = w & 1;
  const int quad = lane >> 4, l16 = lane & 15;
  const int m0 = blockIdx.y * 128, n0 = blockIdx.x * 128;
  f32x4 acc[4][4];
#pragma unroll
  for (int i = 0; i < 4; ++i)
#pragma unroll
    for (int j = 0; j < 4; ++j)
#pragma unroll
      for (int r = 0; r < 4; ++r) acc[i][j][r] = 0.f;

  for (int k0 = 0; k0 < K; k0 += 32) {
    __syncthreads();
#pragma unroll
    for (int p = 0; p < 2; ++p) {
      int v = tid + p * 256;
      int row = v >> 2, kc = (v & 3) * 8;
      *(short8*)&Al[row][kc] = ld8<AF>(Ap, (size_t)(m0 + row) * K + k0 + kc);
      *(short8*)&Bl[row][kc] = ld8<BF>(Bp, (size_t)(n0 + row) * K + k0 + kc);
    }
    __syncthreads();
    short8 a[4];
#pragma unroll
    for (int i = 0; i < 4; ++i)
      a[i] = *(const short8*)&Al[wm * 64 + i * 16 + l16][quad * 8];
#pragma unroll
    for (int j = 0; j < 4; ++j) {
      short8 b = *(const short8*)&Bl[wn * 64 + j * 16 + l16][quad * 8];
#pragma unroll
      for (int i = 0; i < 4; ++i)
        acc[i][j] = __builtin_amdgcn_mfma_f32_16x16x32_bf16(a[i], b, acc[i][j], 0, 0, 0);
    }
  }
#pragma unroll
  for (int i = 0; i < 4; ++i)
#pragma unroll
    for (int j = 0; j < 4; ++j) {
      int row = m0 + wm * 64 + i * 16 + quad * 4;
      int col = n0 + wn * 64 + j * 16 + l16;
#pragma unroll
      for (int r = 0; r < 4; ++r) {
        if constexpr (C32)
          ((float*)Cp)[(size_t)(row + r) * N + col] = acc[i][j][r];
        else
          ((unsigned short*)Cp)[(size_t)(row + r) * N + col] = f2bf(acc[i][j][r]);
      }
    }
}

// ---------------------------------------------------------------------------
// In-place RMS norm per row (register-cached => race-free). w is fp32.
// ---------------------------------------------------------------------------
__global__ __launch_bounds__(256) void rms_norm_ip(
    unsigned short* __restrict__ x, const float* __restrict__ w, int N) {
  unsigned short* row = x + (size_t)blockIdx.x * N;
  float vals[8];
  int cnt = 0;
  float ss = 0.f;
  for (int j = threadIdx.x; j < N; j += 256) {
    float v = bf2f(row[j]);
    vals[cnt++] = v;
    ss += v * v;
  }
#pragma unroll
  for (int d = 1; d < 64; d <<= 1) ss += __shfl_xor(ss, d);
  __shared__ float ws4[4];
  if ((threadIdx.x & 63) == 0) ws4[threadIdx.x >> 6] = ss;
  __syncthreads();
  float tot = ws4[0] + ws4[1] + ws4[2] + ws4[3];
  float scale = rsqrtf(tot / (float)N + 1e-6f);
  cnt = 0;
  for (int j = threadIdx.x; j < N; j += 256)
    row[j] = f2bf(w[j] * vals[cnt++] * scale);
}

// ---------------------------------------------------------------------------
// Build Q (scaled, roped) and K (roped) in (B,H,T,128) from row-major
// q_all (B,T,2048) and k_all (B,T,2048). cos/sin fp32 (T,32).
// ---------------------------------------------------------------------------
__global__ __launch_bounds__(256) void prep_qk(
    const unsigned short* __restrict__ q_all, const unsigned short* __restrict__ k_all,
    const float* __restrict__ cosb, const float* __restrict__ sinb,
    unsigned short* __restrict__ Q, unsigned short* __restrict__ K) {
  const int bt = blockIdx.x;
  const int b = bt >> 11, t = bt & (T_SEQ - 1);
  const unsigned short* qr = q_all + (size_t)bt * (NH * DH);
  const unsigned short* kr = k_all + (size_t)bt * (NH * DH);
  for (int d = threadIdx.x; d < NH * DH; d += 256) {
    int h = d >> 7, dd = d & 127;
    float qv = bf2f(qr[d]);
    float kv = bf2f(kr[d]);
    if (dd < ROPE_R) {
      float c = cosb[t * ROPE_R + dd];
      float s = sinb[t * ROPE_R + dd];
      float qrot = (dd < 16) ? -bf2f(qr[d + 16]) : bf2f(qr[d - 16]);
      float krot = (dd < 16) ? -bf2f(kr[d + 16]) : bf2f(kr[d - 16]);
      qv = qv * c + qrot * s;
      kv = kv * c + krot * s;
    }
    size_t o = ((size_t)(b * NH + h) * T_SEQ + t) * DH + dd;
    Q[o] = f2bf(qv * SCALE_Q);
    K[o] = f2bf(kv);
  }
}

// ---------------------------------------------------------------------------
// Vt[b,h,d,t] = v_all[b,t,h*128+d] * silu(gates[b,t,h*128+d]); LDS transpose.
// ---------------------------------------------------------------------------
__global__ __launch_bounds__(256) void prep_vt(
    const unsigned short* __restrict__ v_all, const unsigned short* __restrict__ gates,
    unsigned short* __restrict__ Vt) {
  __shared__ unsigned short tile[64][130];
  const int bh = blockIdx.y, b = bh >> 4, h = bh & 15;
  const int t0 = blockIdx.x * 64;
  for (int idx = threadIdx.x; idx < 64 * 128; idx += 256) {
    int tt = idx >> 7, dd = idx & 127;
    size_t rowbase = (size_t)(b * T_SEQ + t0 + tt);
    float v = bf2f(v_all[rowbase * (NH * DH) + h * DH + dd]);
    float g = bf2f(gates[rowbase * (NH * DH) + h * DH + dd]);
    float sg = g / (1.f + __expf(-g));
    tile[tt][dd] = f2bf(v * sg);
  }
  __syncthreads();
  for (int idx = threadIdx.x; idx < 64 * 128; idx += 256) {
    int dd = idx >> 6, tt = idx & 63;
    Vt[((size_t)bh * DH + dd) * T_SEQ + t0 + tt] = tile[tt][dd];
  }
}

// ---------------------------------------------------------------------------
// Causal flash attention. Block = 64 Q-rows x one (b,h); 4 waves x 16 rows.
// Q,K: (B,H,T,128) (Q pre-scaled); Vt: (B,H,128,T). Out: (B,T,H*128) bf16.
// ---------------------------------------------------------------------------
__global__ __launch_bounds__(256) void flash_attn(
    const unsigned short* __restrict__ Q, const unsigned short* __restrict__ K,
    const unsigned short* __restrict__ Vt, unsigned short* __restrict__ Out) {
  __shared__ unsigned short P_lds[4][16][96];
  const int qtile = blockIdx.x;
  const int bh = blockIdx.y, b = bh >> 4, h = bh & 15;
  const int lane = threadIdx.x & 63, w = threadIdx.x >> 6;
  const int quad = lane >> 4, l16 = lane & 15;
  const unsigned short* Qb = Q + (size_t)bh * T_SEQ * DH;
  const unsigned short* Kb = K + (size_t)bh * T_SEQ * DH;
  const unsigned short* Vb = Vt + (size_t)bh * DH * T_SEQ;

  const int qrow_a = qtile * 64 + w * 16 + l16;
  short8 qf[4];
#pragma unroll
  for (int kk = 0; kk < 4; ++kk)
    qf[kk] = *(const short8*)&Qb[(size_t)qrow_a * DH + kk * 32 + quad * 8];

  f32x4 O[8];
#pragma unroll
  for (int jn = 0; jn < 8; ++jn)
#pragma unroll
    for (int r = 0; r < 4; ++r) O[jn][r] = 0.f;
  float m_run[4], l_run[4];
#pragma unroll
  for (int r = 0; r < 4; ++r) { m_run[r] = -1e30f; l_run[r] = 0.f; }

  const int ntile = qtile + 1;
  for (int kt = 0; kt < ntile; ++kt) {
    const int kb = kt * 64;
    f32x4 sc[4];
#pragma unroll
    for (int jt = 0; jt < 4; ++jt) {
#pragma unroll
      for (int r = 0; r < 4; ++r) sc[jt][r] = 0.f;
#pragma unroll
      for (int kk = 0; kk < 4; ++kk) {
        short8 kf = *(const short8*)&Kb[(size_t)(kb + jt * 16 + l16) * DH + kk * 32 + quad * 8];
        sc[jt] = __builtin_amdgcn_mfma_f32_16x16x32_bf16(qf[kk], kf, sc[jt], 0, 0, 0);
      }
    }
    if (kb + 63 > qtile * 64 + w * 16) {
#pragma unroll
      for (int jt = 0; jt < 4; ++jt) {
        int key = kb + jt * 16 + l16;
#pragma unroll
        for (int r = 0; r < 4; ++r) {
          int row = qtile * 64 + w * 16 + quad * 4 + r;
          if (key > row) sc[jt][r] = -1e30f;
        }
      }
    }
    float alpha[4], psum[4];
#pragma unroll
    for (int r = 0; r < 4; ++r) {
      float mx = fmaxf(fmaxf(sc[0][r], sc[1][r]), fmaxf(sc[2][r], sc[3][r]));
      mx = fmaxf(mx, __shfl_xor(mx, 1)); mx = fmaxf(mx, __shfl_xor(mx, 2));
      mx = fmaxf(mx, __shfl_xor(mx, 4)); mx = fmaxf(mx, __shfl_xor(mx, 8));
      float mnew = fmaxf(m_run[r], mx);
      alpha[r] = __expf(m_run[r] - mnew);
      m_run[r] = mnew;
      psum[r] = 0.f;
    }
#pragma unroll
    for (int jt = 0; jt < 4; ++jt)
#pragma unroll
      for (int r = 0; r < 4; ++r) {
        float p = __expf(sc[jt][r] - m_run[r]);
        sc[jt][r] = p;
        psum[r] += p;
      }
#pragma unroll
    for (int r = 0; r < 4; ++r) {
      float s = psum[r];
      s += __shfl_xor(s, 1); s += __shfl_xor(s, 2);
      s += __shfl_xor(s, 4); s += __shfl_xor(s, 8);
      l_run[r] = l_run[r] * alpha[r] + s;
    }
#pragma unroll
    for (int jn = 0; jn < 8; ++jn)
#pragma unroll
      for (int r = 0; r < 4; ++r) O[jn][r] *= alpha[r];
#pragma unroll
    for (int jt = 0; jt < 4; ++jt)
#pragma unroll
      for (int r = 0; r < 4; ++r)
        P_lds[w][quad * 4 + r][jt * 16 + l16] = f2bf(sc[jt][r]);
    __syncthreads();
    short8 pa[2];
#pragma unroll
    for (int kk = 0; kk < 2; ++kk)
      pa[kk] = *(const short8*)&P_lds[w][l16][kk * 32 + quad * 8];
#pragma unroll
    for (int jn = 0; jn < 8; ++jn) {
#pragma unroll
      for (int kk = 0; kk < 2; ++kk) {
        short8 vf = *(const short8*)&Vb[(size_t)(jn * 16 + l16) * T_SEQ + kb + kk * 32 + quad * 8];
        O[jn] = __builtin_amdgcn_mfma_f32_16x16x32_bf16(pa[kk], vf, O[jn], 0, 0, 0);
      }
    }
    __syncthreads();
  }
#pragma unroll
  for (int jn = 0; jn < 8; ++jn)
#pragma unroll
    for (int r = 0; r < 4; ++r) {
      int row = qtile * 64 + w * 16 + quad * 4 + r;
      float vv = O[jn][r] / l_run[r];
      Out[((size_t)(b * T_SEQ) + row) * (NH * DH) + h * DH + jn * 16 + l16] = f2bf(vv);
    }
}

// ---------------------------------------------------------------------------
// Inputs fp32; internal bf16; OUTPUT fp32 (reference returns fp32!).
// Workspace plan (74 MiB peak; q_all and attn use d_out (33.5 MB fp32 buf)
// as bf16 scratch (16.8 MB), dead before the final fp32 store):
//   R0 [0,6.29M):  qs (4096x768)          -> later omid (4096x512)
//   R1 [+4.19M):   kvs (4096x512)
//   R2 [+16.78M):  gates (4096x2048)      -> later k_all
//   R3 [+16.78M):  v_all (4096x2048)      -> later Qb
//   R4 [+16.78M):  Vt (B,H,128,T)
//   R5 [+16.78M):  Kb
// ---------------------------------------------------------------------------
extern "C" void kernel_launch(void* const* d_in, const int* in_sizes, int n_in,
                              void* d_out, int out_size, void* d_ws, size_t ws_size,
                              hipStream_t stream) {
  const void*  x     = d_in[0];                       // (B,T,2048) fp32
  const float* cosb  = (const float*)d_in[1];         // (T,32) fp32
  const float* sinb  = (const float*)d_in[2];
  const void*  Wq_s  = d_in[3];                       // (768,2048) fp32
  const float* qs_w  = (const float*)d_in[4];
  const void*  Wkv_s = d_in[5];                       // (512,2048) fp32
  const float* kvs_w = (const float*)d_in[6];
  const void*  Wq_p  = d_in[7];                       // (2048,768) fp32
  const float* Wkv_p = (const float*)d_in[8];         // (4096,512) fp32
  const void*  Wg_p  = d_in[9];                       // (2048,2048) fp32
  const void*  Wo_p  = d_in[10];                      // (512,2048) fp32
  const float* o_w   = (const float*)d_in[11];
  const void*  Wo_s  = d_in[12];                      // (2048,512) fp32
  (void)in_sizes; (void)n_in; (void)out_size; (void)ws_size;

  const int M = B_SZ * T_SEQ;  // 4096
  char* ws = (char*)d_ws;
  unsigned short* qs    = (unsigned short*)(ws + 0);           // R0
  unsigned short* omid  = qs;                                  // R0 (later)
  unsigned short* kvs   = (unsigned short*)(ws + 6291456);     // R1
  unsigned short* gates = (unsigned short*)(ws + 10485760);    // R2
  unsigned short* k_all = gates;                               // R2 (later)
  unsigned short* v_all = (unsigned short*)(ws + 27262976);    // R3
  unsigned short* Qb    = v_all;                               // R3 (later)
  unsigned short* Vt    = (unsigned short*)(ws + 44040192);    // R4
  unsigned short* Kb    = (unsigned short*)(ws + 60817408);    // R5
  unsigned short* q_all = (unsigned short*)d_out;              // d_out scratch (bf16)
  unsigned short* attn  = (unsigned short*)d_out;              // d_out scratch (bf16)

  dim3 blk(256);
  // shared projections + gates from x (fp32 A, fp32 B)
  gemm_bt<true, true, false><<<dim3(768 / 128, M / 128), blk, 0, stream>>>(x, Wq_s, qs, M, 768, 2048);
  gemm_bt<true, true, false><<<dim3(512 / 128, M / 128), blk, 0, stream>>>(x, Wkv_s, kvs, M, 512, 2048);
  gemm_bt<true, true, false><<<dim3(2048 / 128, M / 128), blk, 0, stream>>>(x, Wg_p, gates, M, 2048, 2048);
  rms_norm_ip<<<M, blk, 0, stream>>>(qs, qs_w, 768);
  rms_norm_ip<<<M, blk, 0, stream>>>(kvs, kvs_w, 512);
  // private projections (bf16 A, fp32 B)
  gemm_bt<false, true, false><<<dim3(2048 / 128, M / 128), blk, 0, stream>>>(qs, Wq_p, q_all, M, 2048, 768);
  gemm_bt<false, true, false><<<dim3(2048 / 128, M / 128), blk, 0, stream>>>(
      kvs, Wkv_p + (size_t)2048 * 512, v_all, M, 2048, 512);
  prep_vt<<<dim3(T_SEQ / 64, B_SZ * NH), blk, 0, stream>>>(v_all, gates, Vt);   // gates, v_all die
  gemm_bt<false, true, false><<<dim3(2048 / 128, M / 128), blk, 0, stream>>>(kvs, Wkv_p, k_all, M, 2048, 512);
  prep_qk<<<M, blk, 0, stream>>>(q_all, k_all, cosb, sinb, Qb, Kb);             // q_all, k_all die
  // attention (d_out as bf16 scratch)
  flash_attn<<<dim3(T_SEQ / 64, B_SZ * NH), blk, 0, stream>>>(Qb, Kb, Vt, attn);
  // output projections; final store is fp32 into d_out
  gemm_bt<false, true, false><<<dim3(512 / 128, M / 128), blk, 0, stream>>>(attn, Wo_p, omid, M, 512, 2048);
  rms_norm_ip<<<M, blk, 0, stream>>>(omid, o_w, 512);
  gemm_bt<false, true, true><<<dim3(2048 / 128, M / 128), blk, 0, stream>>>(omid, Wo_s, d_out, M, 2048, 512);
}

// Round 7
// 942.030 us; speedup vs baseline: 1.2135x; 1.2135x over previous
//
#include <hip/hip_runtime.h>
#include <stdint.h>

typedef __attribute__((ext_vector_type(8))) short short8;
typedef __attribute__((ext_vector_type(4))) float f32x4;

__device__ __forceinline__ float bf2f(unsigned short u) {
  union { unsigned int i; float f; } v; v.i = ((unsigned int)u) << 16; return v.f;
}
__device__ __forceinline__ unsigned short f2bf(float f) {
  union { float f; unsigned int i; } v; v.f = f;
  unsigned int u = v.i;
  return (unsigned short)((u + 0x7fffu + ((u >> 16) & 1u)) >> 16);
}

#define B_SZ 2
#define T_SEQ 2048
#define NH 16
#define DH 128
#define ROPE_R 32
#define SCALE_Q 0.08838834764831845f

// Load 8 consecutive elements as bf16 fragment; F=true -> source is fp32.
template <bool F>
__device__ __forceinline__ short8 ld8(const void* base, size_t idx) {
  if constexpr (F) {
    const float* p = (const float*)base + idx;
    f32x4 a = *(const f32x4*)p;
    f32x4 b = *(const f32x4*)(p + 4);
    short8 r;
    r[0] = (short)f2bf(a[0]); r[1] = (short)f2bf(a[1]);
    r[2] = (short)f2bf(a[2]); r[3] = (short)f2bf(a[3]);
    r[4] = (short)f2bf(b[0]); r[5] = (short)f2bf(b[1]);
    r[6] = (short)f2bf(b[2]); r[7] = (short)f2bf(b[3]);
    return r;
  } else {
    return *(const short8*)((const unsigned short*)base + idx);
  }
}

// ---------------------------------------------------------------------------
// C[M][N] = A[M][K] @ B[N][K]^T ; bf16 internal, fp32 accum.
// AF/BF: operand source is fp32 (converted during LDS staging).
// C32: store C as fp32 (final output) else bf16.
// ---------------------------------------------------------------------------
template <bool AF, bool BF, bool C32>
__global__ __launch_bounds__(256) void gemm_bt(
    const void* __restrict__ Ap, const void* __restrict__ Bp,
    void* __restrict__ Cp, int M, int N, int K) {
  __shared__ unsigned short Al[128][40];
  __shared__ unsigned short Bl[128][40];
  const int tid = threadIdx.x;
  const int lane = tid & 63, w = tid >> 6;
  const int wm = w >> 1, wn = w & 1;
  const int quad = lane >> 4, l16 = lane & 15;
  const int m0 = blockIdx.y * 128, n0 = blockIdx.x * 128;
  f32x4 acc[4][4];
#pragma unroll
  for (int i = 0; i < 4; ++i)
#pragma unroll
    for (int j = 0; j < 4; ++j)
#pragma unroll
      for (int r = 0; r < 4; ++r) acc[i][j][r] = 0.f;

  for (int k0 = 0; k0 < K; k0 += 32) {
    __syncthreads();
#pragma unroll
    for (int p = 0; p < 2; ++p) {
      int v = tid + p * 256;
      int row = v >> 2, kc = (v & 3) * 8;
      *(short8*)&Al[row][kc] = ld8<AF>(Ap, (size_t)(m0 + row) * K + k0 + kc);
      *(short8*)&Bl[row][kc] = ld8<BF>(Bp, (size_t)(n0 + row) * K + k0 + kc);
    }
    __syncthreads();
    short8 a[4];
#pragma unroll
    for (int i = 0; i < 4; ++i)
      a[i] = *(const short8*)&Al[wm * 64 + i * 16 + l16][quad * 8];
#pragma unroll
    for (int j = 0; j < 4; ++j) {
      short8 b = *(const short8*)&Bl[wn * 64 + j * 16 + l16][quad * 8];
#pragma unroll
      for (int i = 0; i < 4; ++i)
        acc[i][j] = __builtin_amdgcn_mfma_f32_16x16x32_bf16(a[i], b, acc[i][j], 0, 0, 0);
    }
  }
#pragma unroll
  for (int i = 0; i < 4; ++i)
#pragma unroll
    for (int j = 0; j < 4; ++j) {
      int row = m0 + wm * 64 + i * 16 + quad * 4;
      int col = n0 + wn * 64 + j * 16 + l16;
#pragma unroll
      for (int r = 0; r < 4; ++r) {
        if constexpr (C32)
          ((float*)Cp)[(size_t)(row + r) * N + col] = acc[i][j][r];
        else
          ((unsigned short*)Cp)[(size_t)(row + r) * N + col] = f2bf(acc[i][j][r]);
      }
    }
}

// ---------------------------------------------------------------------------
__global__ __launch_bounds__(256) void rms_norm_ip(
    unsigned short* __restrict__ x, const float* __restrict__ w, int N) {
  unsigned short* row = x + (size_t)blockIdx.x * N;
  float vals[8];
  int cnt = 0;
  float ss = 0.f;
  for (int j = threadIdx.x; j < N; j += 256) {
    float v = bf2f(row[j]);
    vals[cnt++] = v;
    ss += v * v;
  }
#pragma unroll
  for (int d = 1; d < 64; d <<= 1) ss += __shfl_xor(ss, d);
  __shared__ float ws4[4];
  if ((threadIdx.x & 63) == 0) ws4[threadIdx.x >> 6] = ss;
  __syncthreads();
  float tot = ws4[0] + ws4[1] + ws4[2] + ws4[3];
  float scale = rsqrtf(tot / (float)N + 1e-6f);
  cnt = 0;
  for (int j = threadIdx.x; j < N; j += 256)
    row[j] = f2bf(w[j] * vals[cnt++] * scale);
}

// ---------------------------------------------------------------------------
__global__ __launch_bounds__(256) void prep_qk(
    const unsigned short* __restrict__ q_all, const unsigned short* __restrict__ k_all,
    const float* __restrict__ cosb, const float* __restrict__ sinb,
    unsigned short* __restrict__ Q, unsigned short* __restrict__ K) {
  const int bt = blockIdx.x;
  const int b = bt >> 11, t = bt & (T_SEQ - 1);
  const unsigned short* qr = q_all + (size_t)bt * (NH * DH);
  const unsigned short* kr = k_all + (size_t)bt * (NH * DH);
  for (int d = threadIdx.x; d < NH * DH; d += 256) {
    int h = d >> 7, dd = d & 127;
    float qv = bf2f(qr[d]);
    float kv = bf2f(kr[d]);
    if (dd < ROPE_R) {
      float c = cosb[t * ROPE_R + dd];
      float s = sinb[t * ROPE_R + dd];
      float qrot = (dd < 16) ? -bf2f(qr[d + 16]) : bf2f(qr[d - 16]);
      float krot = (dd < 16) ? -bf2f(kr[d + 16]) : bf2f(kr[d - 16]);
      qv = qv * c + qrot * s;
      kv = kv * c + krot * s;
    }
    size_t o = ((size_t)(b * NH + h) * T_SEQ + t) * DH + dd;
    Q[o] = f2bf(qv * SCALE_Q);
    K[o] = f2bf(kv);
  }
}

// ---------------------------------------------------------------------------
__global__ __launch_bounds__(256) void prep_vt(
    const unsigned short* __restrict__ v_all, const unsigned short* __restrict__ gates,
    unsigned short* __restrict__ Vt) {
  __shared__ unsigned short tile[64][130];
  const int bh = blockIdx.y, b = bh >> 4, h = bh & 15;
  const int t0 = blockIdx.x * 64;
  for (int idx = threadIdx.x; idx < 64 * 128; idx += 256) {
    int tt = idx >> 7, dd = idx & 127;
    size_t rowbase = (size_t)(b * T_SEQ + t0 + tt);
    float v = bf2f(v_all[rowbase * (NH * DH) + h * DH + dd]);
    float g = bf2f(gates[rowbase * (NH * DH) + h * DH + dd]);
    float sg = g / (1.f + __expf(-g));
    tile[tt][dd] = f2bf(v * sg);
  }
  __syncthreads();
  for (int idx = threadIdx.x; idx < 64 * 128; idx += 256) {
    int dd = idx >> 6, tt = idx & 63;
    Vt[((size_t)bh * DH + dd) * T_SEQ + t0 + tt] = tile[tt][dd];
  }
}

// ---------------------------------------------------------------------------
// Online-softmax update for one 64-row q-tile against the staged 64-key tile.
// ---------------------------------------------------------------------------
__device__ __forceinline__ void attn_update(
    const unsigned short (*Kl)[132], const unsigned short (*Vl)[68],
    unsigned short (*Pw)[96], const short8* qf, int qt, int kb, bool diag,
    int w, int quad, int l16, f32x4* O, float* m_run, float* l_run) {
  f32x4 sc[4];
#pragma unroll
  for (int jt = 0; jt < 4; ++jt) {
#pragma unroll
    for (int r = 0; r < 4; ++r) sc[jt][r] = 0.f;
#pragma unroll
    for (int kk = 0; kk < 4; ++kk) {
      short8 kf = *(const short8*)&Kl[jt * 16 + l16][kk * 32 + quad * 8];
      sc[jt] = __builtin_amdgcn_mfma_f32_16x16x32_bf16(qf[kk], kf, sc[jt], 0, 0, 0);
    }
  }
  if (diag) {
#pragma unroll
    for (int jt = 0; jt < 4; ++jt) {
      int key = kb + jt * 16 + l16;
#pragma unroll
      for (int r = 0; r < 4; ++r) {
        int row = qt * 64 + w * 16 + quad * 4 + r;
        if (key > row) sc[jt][r] = -1e30f;
      }
    }
  }
  float alpha[4], psum[4];
#pragma unroll
  for (int r = 0; r < 4; ++r) {
    float mx = fmaxf(fmaxf(sc[0][r], sc[1][r]), fmaxf(sc[2][r], sc[3][r]));
    mx = fmaxf(mx, __shfl_xor(mx, 1)); mx = fmaxf(mx, __shfl_xor(mx, 2));
    mx = fmaxf(mx, __shfl_xor(mx, 4)); mx = fmaxf(mx, __shfl_xor(mx, 8));
    float mnew = fmaxf(m_run[r], mx);
    alpha[r] = __expf(m_run[r] - mnew);
    m_run[r] = mnew;
    psum[r] = 0.f;
  }
#pragma unroll
  for (int jt = 0; jt < 4; ++jt)
#pragma unroll
    for (int r = 0; r < 4; ++r) {
      float p = __expf(sc[jt][r] - m_run[r]);
      sc[jt][r] = p;
      psum[r] += p;
    }
#pragma unroll
  for (int r = 0; r < 4; ++r) {
    float s = psum[r];
    s += __shfl_xor(s, 1); s += __shfl_xor(s, 2);
    s += __shfl_xor(s, 4); s += __shfl_xor(s, 8);
    l_run[r] = l_run[r] * alpha[r] + s;
  }
#pragma unroll
  for (int jn = 0; jn < 8; ++jn)
#pragma unroll
    for (int r = 0; r < 4; ++r) O[jn][r] *= alpha[r];
  // P: C-layout -> per-wave LDS -> A-layout (no cross-wave sync needed)
#pragma unroll
  for (int jt = 0; jt < 4; ++jt)
#pragma unroll
    for (int r = 0; r < 4; ++r)
      Pw[quad * 4 + r][jt * 16 + l16] = f2bf(sc[jt][r]);
  short8 pa[2];
#pragma unroll
  for (int kk = 0; kk < 2; ++kk)
    pa[kk] = *(const short8*)&Pw[l16][kk * 32 + quad * 8];
#pragma unroll
  for (int jn = 0; jn < 8; ++jn) {
#pragma unroll
    for (int kk = 0; kk < 2; ++kk) {
      short8 vf = *(const short8*)&Vl[jn * 16 + l16][kk * 32 + quad * 8];
      O[jn] = __builtin_amdgcn_mfma_f32_16x16x32_bf16(pa[kk], vf, O[jn], 0, 0, 0);
    }
  }
}

// ---------------------------------------------------------------------------
// Causal flash attention with q-tile PAIRING + block-level K/V LDS staging +
// register-prefetch double buffer + XCD-aware block swizzle.
// Block handles q-tiles qa=i and qb=31-i of one (b,h): uniform 33 updates.
// Q,K: (B,H,T,128) (Q pre-scaled); Vt: (B,H,128,T). Out: (B,T,H*128) bf16.
// Grid: 512 blocks, 1-D. bh = (l&7) + 8*((l>>3)>>4) keeps each bh on one XCD.
// ---------------------------------------------------------------------------
__global__ __launch_bounds__(256) void flash_attn(
    const unsigned short* __restrict__ Q, const unsigned short* __restrict__ K,
    const unsigned short* __restrict__ Vt, unsigned short* __restrict__ Out) {
  __shared__ unsigned short Kl[64][132];
  __shared__ unsigned short Vl[128][68];
  __shared__ unsigned short P_lds[4][16][96];
  const int l = blockIdx.x;
  const int s = l & 7, qq = l >> 3;
  const int bh = s + 8 * (qq >> 4);
  const int qp = qq & 15;
  const int qa = qp, qb = 31 - qp;
  const int b = bh >> 4, h = bh & 15;
  const int tid = threadIdx.x;
  const int lane = tid & 63, w = tid >> 6;
  const int quad = lane >> 4, l16 = lane & 15;
  const unsigned short* Qb = Q + (size_t)bh * T_SEQ * DH;
  const unsigned short* Kb = K + (size_t)bh * T_SEQ * DH;
  const unsigned short* Vb = Vt + (size_t)bh * DH * T_SEQ;

  short8 qfA[4], qfB[4];
  const int rowA = qa * 64 + w * 16 + l16;
  const int rowB = qb * 64 + w * 16 + l16;
#pragma unroll
  for (int kk = 0; kk < 4; ++kk) {
    qfA[kk] = *(const short8*)&Qb[(size_t)rowA * DH + kk * 32 + quad * 8];
    qfB[kk] = *(const short8*)&Qb[(size_t)rowB * DH + kk * 32 + quad * 8];
  }

  f32x4 OA[8], OB[8];
  float mA[4], lA[4], mB[4], lB[4];
#pragma unroll
  for (int jn = 0; jn < 8; ++jn)
#pragma unroll
    for (int r = 0; r < 4; ++r) { OA[jn][r] = 0.f; OB[jn][r] = 0.f; }
#pragma unroll
  for (int r = 0; r < 4; ++r) { mA[r] = -1e30f; lA[r] = 0.f; mB[r] = -1e30f; lB[r] = 0.f; }

  short8 krg[4], vrg[4];
  // prologue: stage tile 0
#pragma unroll
  for (int p = 0; p < 4; ++p) {
    int id = tid + p * 256;
    krg[p] = *(const short8*)&Kb[(size_t)(id >> 4) * DH + (id & 15) * 8];
    vrg[p] = *(const short8*)&Vb[(size_t)(id >> 3) * T_SEQ + (id & 7) * 8];
  }
#pragma unroll
  for (int p = 0; p < 4; ++p) {
    int id = tid + p * 256;
    *(short8*)&Kl[id >> 4][(id & 15) * 8] = krg[p];
    *(short8*)&Vl[id >> 3][(id & 7) * 8] = vrg[p];
  }
  __syncthreads();

  const int last = qb;
  for (int kt = 0; kt <= last; ++kt) {
    const int kb = kt * 64;
    if (kt < last) {  // prefetch next tile into registers (overlaps compute)
      const int nb = kb + 64;
#pragma unroll
      for (int p = 0; p < 4; ++p) {
        int id = tid + p * 256;
        krg[p] = *(const short8*)&Kb[(size_t)(nb + (id >> 4)) * DH + (id & 15) * 8];
        vrg[p] = *(const short8*)&Vb[(size_t)(id >> 3) * T_SEQ + nb + (id & 7) * 8];
      }
    }
    if (kt <= qa)
      attn_update(Kl, Vl, P_lds[w], qfA, qa, kb, kt == qa, w, quad, l16, OA, mA, lA);
    attn_update(Kl, Vl, P_lds[w], qfB, qb, kb, kt == last, w, quad, l16, OB, mB, lB);
    if (kt < last) {
      __syncthreads();  // all waves done reading Kl/Vl
#pragma unroll
      for (int p = 0; p < 4; ++p) {
        int id = tid + p * 256;
        *(short8*)&Kl[id >> 4][(id & 15) * 8] = krg[p];
        *(short8*)&Vl[id >> 3][(id & 7) * 8] = vrg[p];
      }
      __syncthreads();  // staging visible
    }
  }

#pragma unroll
  for (int jn = 0; jn < 8; ++jn)
#pragma unroll
    for (int r = 0; r < 4; ++r) {
      int ra = qa * 64 + w * 16 + quad * 4 + r;
      int rb = qb * 64 + w * 16 + quad * 4 + r;
      Out[((size_t)(b * T_SEQ) + ra) * (NH * DH) + h * DH + jn * 16 + l16] =
          f2bf(OA[jn][r] / lA[r]);
      Out[((size_t)(b * T_SEQ) + rb) * (NH * DH) + h * DH + jn * 16 + l16] =
          f2bf(OB[jn][r] / lB[r]);
    }
}

// ---------------------------------------------------------------------------
// Inputs fp32; internal bf16; OUTPUT fp32.
// Workspace plan (74 MiB peak; q_all and attn use d_out as bf16 scratch):
//   R0 [0,6.29M):  qs -> later omid ; R1: kvs ; R2: gates -> k_all ;
//   R3: v_all -> Qb ; R4: Vt ; R5: Kb
// ---------------------------------------------------------------------------
extern "C" void kernel_launch(void* const* d_in, const int* in_sizes, int n_in,
                              void* d_out, int out_size, void* d_ws, size_t ws_size,
                              hipStream_t stream) {
  const void*  x     = d_in[0];
  const float* cosb  = (const float*)d_in[1];
  const float* sinb  = (const float*)d_in[2];
  const void*  Wq_s  = d_in[3];
  const float* qs_w  = (const float*)d_in[4];
  const void*  Wkv_s = d_in[5];
  const float* kvs_w = (const float*)d_in[6];
  const void*  Wq_p  = d_in[7];
  const float* Wkv_p = (const float*)d_in[8];
  const void*  Wg_p  = d_in[9];
  const void*  Wo_p  = d_in[10];
  const float* o_w   = (const float*)d_in[11];
  const void*  Wo_s  = d_in[12];
  (void)in_sizes; (void)n_in; (void)out_size; (void)ws_size;

  const int M = B_SZ * T_SEQ;  // 4096
  char* ws = (char*)d_ws;
  unsigned short* qs    = (unsigned short*)(ws + 0);
  unsigned short* omid  = qs;
  unsigned short* kvs   = (unsigned short*)(ws + 6291456);
  unsigned short* gates = (unsigned short*)(ws + 10485760);
  unsigned short* k_all = gates;
  unsigned short* v_all = (unsigned short*)(ws + 27262976);
  unsigned short* Qb    = v_all;
  unsigned short* Vt    = (unsigned short*)(ws + 44040192);
  unsigned short* Kb    = (unsigned short*)(ws + 60817408);
  unsigned short* q_all = (unsigned short*)d_out;
  unsigned short* attn  = (unsigned short*)d_out;

  dim3 blk(256);
  gemm_bt<true, true, false><<<dim3(768 / 128, M / 128), blk, 0, stream>>>(x, Wq_s, qs, M, 768, 2048);
  gemm_bt<true, true, false><<<dim3(512 / 128, M / 128), blk, 0, stream>>>(x, Wkv_s, kvs, M, 512, 2048);
  gemm_bt<true, true, false><<<dim3(2048 / 128, M / 128), blk, 0, stream>>>(x, Wg_p, gates, M, 2048, 2048);
  rms_norm_ip<<<M, blk, 0, stream>>>(qs, qs_w, 768);
  rms_norm_ip<<<M, blk, 0, stream>>>(kvs, kvs_w, 512);
  gemm_bt<false, true, false><<<dim3(2048 / 128, M / 128), blk, 0, stream>>>(qs, Wq_p, q_all, M, 2048, 768);
  gemm_bt<false, true, false><<<dim3(2048 / 128, M / 128), blk, 0, stream>>>(
      kvs, Wkv_p + (size_t)2048 * 512, v_all, M, 2048, 512);
  prep_vt<<<dim3(T_SEQ / 64, B_SZ * NH), blk, 0, stream>>>(v_all, gates, Vt);
  gemm_bt<false, true, false><<<dim3(2048 / 128, M / 128), blk, 0, stream>>>(kvs, Wkv_p, k_all, M, 2048, 512);
  prep_qk<<<M, blk, 0, stream>>>(q_all, k_all, cosb, sinb, Qb, Kb);
  flash_attn<<<dim3(512), blk, 0, stream>>>(Qb, Kb, Vt, attn);
  gemm_bt<false, true, false><<<dim3(512 / 128, M / 128), blk, 0, stream>>>(attn, Wo_p, omid, M, 512, 2048);
  rms_norm_ip<<<M, blk, 0, stream>>>(omid, o_w, 512);
  gemm_bt<false, true, true><<<dim3(2048 / 128, M / 128), blk, 0, stream>>>(omid, Wo_s, d_out, M, 2048, 512);
}